// Round 4
// baseline (560.039 us; speedup 1.0000x reference)
//
#include <hip/hip_runtime.h>
#include <hip/hip_fp16.h>

// NeRF ray-marching renderer, MI355X — round 4.
//  - Path-coherent ray ordering: two-pass counting (radix) sort on a 22-bit
//    key = [entry cell 11b][exit cell 11b] (16x8x16 quantization of the AABB
//    hit points). Rays in a wave then sample near-identical voxels at every
//    aligned step -> gathers coalesce, L1/L2 reuse.
//  - SPLIT=4 segments per ray (compositing is associative) -> 16384 waves.
//  - u8 quad-cell grid (2 dwordx4 gathers/step) + next-step prefetch.

constexpr int   kG     = 128;
constexpr int   kG3    = kG * kG * kG;
constexpr int   kSteps = 128;
constexpr int   kNRays = 262144;          // 2^18
constexpr int   kNB    = 128;             // tier-B direction bins
constexpr int   kNBuckets = kNB * kNB;
constexpr int   kRB    = 2048;            // radix buckets per pass (11 bits)
constexpr float kBminX = -1.0f, kBminY = -0.5f, kBminZ = -1.0f;
constexpr float kBmaxX =  1.0f, kBmaxY =  0.5f, kBmaxZ =  1.0f;
constexpr float kSx = 63.5f, kSy = 127.0f, kSz = 63.5f;   // (G-1)/extent
constexpr float kMinNear = 0.05f;
constexpr float kTTh     = 1e-4f;

// ---------------- shared helpers ------------------------------------------
__device__ __forceinline__ void slabNearFar(
    float ox, float oy, float oz, float dx, float dy, float dz,
    float& near_, float& far_)
{
    float sdx = (fabsf(dx) < 1e-9f) ? 1e-9f : dx;
    float sdy = (fabsf(dy) < 1e-9f) ? 1e-9f : dy;
    float sdz = (fabsf(dz) < 1e-9f) ? 1e-9f : dz;
    float t1x = (kBminX - ox) / sdx, t2x = (kBmaxX - ox) / sdx;
    float t1y = (kBminY - oy) / sdy, t2y = (kBmaxY - oy) / sdy;
    float t1z = (kBminZ - oz) / sdz, t2z = (kBmaxZ - oz) / sdz;
    near_ = fmaxf(fmaxf(fminf(t1x, t2x), fminf(t1y, t2y)), fminf(t1z, t2z));
    far_  = fminf(fminf(fmaxf(t1x, t2x), fmaxf(t1y, t2y)), fmaxf(t1z, t2z));
    near_ = fmaxf(near_, kMinNear);
    far_  = fmaxf(far_, near_ + 1e-6f);
}

__device__ __forceinline__ void stepAddr(
    float near_, float dt, float ox, float oy, float oz,
    float dx, float dy, float dz, int s,
    int& cell, float& fx, float& fy, float& fz)
{
    float t  = fmaf((float)s + 0.5f, dt, near_);
    float px = fmaf(t, dx, ox), py = fmaf(t, dy, oy), pz = fmaf(t, dz, oz);
    float ux = fminf(fmaxf((px - kBminX) * kSx, 0.0f), 127.0f);
    float uy = fminf(fmaxf((py - kBminY) * kSy, 0.0f), 127.0f);
    float uz = fminf(fmaxf((pz - kBminZ) * kSz, 0.0f), 127.0f);
    float u0x = fminf(floorf(ux), 126.0f);
    float u0y = fminf(floorf(uy), 126.0f);
    float u0z = fminf(floorf(uz), 126.0f);
    fx = ux - u0x; fy = uy - u0y; fz = uz - u0z;
    cell = ((int)u0x << 14) + ((int)u0y << 7) + (int)u0z;
}

// ---------------- repack: quad u8 cells -----------------------------------
__device__ __forceinline__ unsigned packv(const float* __restrict__ sig,
                                          const float* __restrict__ rgb, int idx)
{
    unsigned s = (unsigned)__float2int_rn(fminf(fmaxf(sig[idx], 0.f), 1.f) * 255.f);
    unsigned r = (unsigned)__float2int_rn(fminf(fmaxf(rgb[3*idx+0], 0.f), 1.f) * 255.f);
    unsigned g = (unsigned)__float2int_rn(fminf(fmaxf(rgb[3*idx+1], 0.f), 1.f) * 255.f);
    unsigned b = (unsigned)__float2int_rn(fminf(fmaxf(rgb[3*idx+2], 0.f), 1.f) * 255.f);
    return s | (r << 8) | (g << 16) | (b << 24);
}

__global__ __launch_bounds__(256) void repack_quad_k(
    const float* __restrict__ sig, const float* __restrict__ rgb,
    uint4* __restrict__ out)
{
    int i = blockIdx.x * 256 + threadIdx.x;
    if (i >= kG3) return;
    int iz = i & 127, iy = (i >> 7) & 127, ix = i >> 14;
    int z1 = min(iz + 1, 127), y1 = min(iy + 1, 127);
    int b00 = (ix << 14) + (iy << 7) + iz;
    int b01 = (ix << 14) + (iy << 7) + z1;
    int b10 = (ix << 14) + (y1 << 7) + iz;
    int b11 = (ix << 14) + (y1 << 7) + z1;
    out[i] = make_uint4(packv(sig, rgb, b00), packv(sig, rgb, b01),
                        packv(sig, rgb, b10), packv(sig, rgb, b11));
}

// ---------------- Tier-A radix sort on entry/exit key ---------------------
__global__ __launch_bounds__(256) void zero4096_k(int* __restrict__ p)
{
    int i = blockIdx.x * 256 + threadIdx.x;
    if (i < 2 * kRB) p[i] = 0;
}

__device__ __forceinline__ int cell11(float x, float y, float z)
{
    int cx = min(15, max(0, (int)((x - kBminX) * 8.0f)));
    int cy = min(7,  max(0, (int)((y - kBminY) * 8.0f)));
    int cz = min(15, max(0, (int)((z - kBminZ) * 8.0f)));
    return (cx << 7) | (cy << 4) | cz;
}

__global__ __launch_bounds__(256) void nfkey_k(
    const float* __restrict__ rays_o, const float* __restrict__ rays_d,
    int* __restrict__ keys, int* __restrict__ hist_lo, int* __restrict__ hist_hi)
{
    int i = blockIdx.x * 256 + threadIdx.x;
    if (i >= kNRays) return;
    float ox = rays_o[3 * i + 0], oy = rays_o[3 * i + 1], oz = rays_o[3 * i + 2];
    float dx = rays_d[3 * i + 0], dy = rays_d[3 * i + 1], dz = rays_d[3 * i + 2];
    float near_, far_;
    slabNearFar(ox, oy, oz, dx, dy, dz, near_, far_);
    int ke = cell11(fmaf(near_, dx, ox), fmaf(near_, dy, oy), fmaf(near_, dz, oz));
    int kx = cell11(fmaf(far_,  dx, ox), fmaf(far_,  dy, oy), fmaf(far_,  dz, oz));
    int key = (ke << 11) | kx;
    keys[i] = key;
    atomicAdd(&hist_lo[key & (kRB - 1)], 1);
    atomicAdd(&hist_hi[key >> 11], 1);
}

// exclusive scan of NB ints with one 256-thread block
template <int NB>
__global__ __launch_bounds__(256) void scanT_k(
    const int* __restrict__ hist, int* __restrict__ base)
{
    __shared__ int part[256];
    int t = threadIdx.x;
    int s = 0;
    for (int k = 0; k < NB / 256; ++k) s += hist[t * (NB / 256) + k];
    part[t] = s;
    __syncthreads();
    if (t == 0) {
        int run = 0;
        for (int k = 0; k < 256; ++k) { int v = part[k]; part[k] = run; run += v; }
    }
    __syncthreads();
    int run = part[t];
    for (int k = 0; k < NB / 256; ++k) {
        int idx = t * (NB / 256) + k;
        base[idx] = run;
        run += hist[idx];
    }
}

__global__ __launch_bounds__(256) void scatter_lo_k(
    const int* __restrict__ keys, int* __restrict__ base,
    int* __restrict__ perm1)
{
    int i = blockIdx.x * 256 + threadIdx.x;
    if (i >= kNRays) return;
    int pos = atomicAdd(&base[keys[i] & (kRB - 1)], 1);
    perm1[pos] = i;
}

__global__ __launch_bounds__(256) void scatter_hi_k(
    const int* __restrict__ keys, const int* __restrict__ perm1,
    int* __restrict__ base, int* __restrict__ perm)
{
    int j = blockIdx.x * 256 + threadIdx.x;
    if (j >= kNRays) return;
    int i = perm1[j];
    int pos = atomicAdd(&base[keys[i] >> 11], 1);
    perm[pos] = i;
}

// ---------------- Tier-B direction sort (round-2/3 path) ------------------
__global__ __launch_bounds__(256) void zero_hist_k(int* __restrict__ hist)
{
    int i = blockIdx.x * 256 + threadIdx.x;
    if (i < kNBuckets) hist[i] = 0;
}

__global__ __launch_bounds__(256) void key_hist_k(
    const float* __restrict__ rays_d, int* __restrict__ keys,
    int* __restrict__ hist)
{
    int i = blockIdx.x * 256 + threadIdx.x;
    if (i >= kNRays) return;
    float dx = rays_d[3 * i + 0], dy = rays_d[3 * i + 1];
    int qx = (int)((dx * 0.625f + 0.5f) * (float)kNB);
    int qy = (int)((dy * 0.625f + 0.5f) * (float)kNB);
    qx = min(kNB - 1, max(0, qx));
    qy = min(kNB - 1, max(0, qy));
    int key = qx * kNB + qy;
    keys[i] = key;
    atomicAdd(&hist[key], 1);
}

__global__ __launch_bounds__(256) void scatter_k(
    const int* __restrict__ keys, int* __restrict__ base,
    int* __restrict__ perm)
{
    int i = blockIdx.x * 256 + threadIdx.x;
    if (i >= kNRays) return;
    int pos = atomicAdd(&base[keys[i]], 1);
    perm[pos] = i;
}

// ---------------- main render (quad cells, split, prefetch) ---------------
#define UB0(u) ((float)((u) & 0xffu))
#define UB1(u) ((float)(((u) >> 8) & 0xffu))
#define UB2(u) ((float)(((u) >> 16) & 0xffu))
#define UB3(u) ((float)((u) >> 24))

template <int SPLIT>
__global__ __launch_bounds__(256, 8) void render_q_k(
    const float* __restrict__ rays_o, const float* __restrict__ rays_d,
    const uint4* __restrict__ grid, const int* __restrict__ perm,
    float4* __restrict__ pRGBW, float* __restrict__ pT)
{
    int j = blockIdx.x * 256 + threadIdx.x;
    if (j >= kNRays * SPLIT) return;
    int seg = j >> 18;                 // kNRays = 2^18
    int sj  = j & (kNRays - 1);
    int ray = perm[sj];

    float ox = rays_o[3 * ray + 0], oy = rays_o[3 * ray + 1], oz = rays_o[3 * ray + 2];
    float dx = rays_d[3 * ray + 0], dy = rays_d[3 * ray + 1], dz = rays_d[3 * ray + 2];
    float near_, far_;
    slabNearFar(ox, oy, oz, dx, dy, dz, near_, far_);
    float dt  = (far_ - near_) * (1.0f / (float)kSteps);
    float dtq = dt * (1.0f / 255.0f);

    const int nsteps = kSteps / SPLIT;
    const int s0     = seg * nsteps;

    int   c;  float fx, fy, fz;
    stepAddr(near_, dt, ox, oy, oz, dx, dy, dz, s0, c, fx, fy, fz);
    uint4 q0 = grid[c];
    uint4 q1 = grid[c + (1 << 14)];

    float T = 1.0f, wsum = 0.0f, ar = 0.0f, ag = 0.0f, ab = 0.0f;

    for (int s = 0; s < nsteps; ++s) {
        int   cn; float nfx, nfy, nfz;
        int   sn = s0 + min(s + 1, nsteps - 1);
        stepAddr(near_, dt, ox, oy, oz, dx, dy, dz, sn, cn, nfx, nfy, nfz);
        uint4 m0 = grid[cn];
        uint4 m1 = grid[cn + (1 << 14)];

        float wz0 = 1.0f - fz, wy0 = 1.0f - fy;
        float w00 = wy0 * wz0, w01 = wy0 * fz, w10 = fy * wz0, w11 = fy * fz;

        float sA = w00 * UB0(q0.x) + w01 * UB0(q0.y) + w10 * UB0(q0.z) + w11 * UB0(q0.w);
        float sB = w00 * UB0(q1.x) + w01 * UB0(q1.y) + w10 * UB0(q1.z) + w11 * UB0(q1.w);
        float rA = w00 * UB1(q0.x) + w01 * UB1(q0.y) + w10 * UB1(q0.z) + w11 * UB1(q0.w);
        float rB = w00 * UB1(q1.x) + w01 * UB1(q1.y) + w10 * UB1(q1.z) + w11 * UB1(q1.w);
        float gA = w00 * UB2(q0.x) + w01 * UB2(q0.y) + w10 * UB2(q0.z) + w11 * UB2(q0.w);
        float gB = w00 * UB2(q1.x) + w01 * UB2(q1.y) + w10 * UB2(q1.z) + w11 * UB2(q1.w);
        float bA = w00 * UB3(q0.x) + w01 * UB3(q0.y) + w10 * UB3(q0.z) + w11 * UB3(q0.w);
        float bB = w00 * UB3(q1.x) + w01 * UB3(q1.y) + w10 * UB3(q1.z) + w11 * UB3(q1.w);

        float sv = fmaf(fx, sB - sA, sA);      // raw counts in [0,255]
        float rv = fmaf(fx, rB - rA, rA);
        float gv = fmaf(fx, gB - gA, gA);
        float bv = fmaf(fx, bB - bA, bA);

        float sigr  = (sv > 2.55f) ? sv : 0.0f;            // sigma > 0.01
        float alpha = 1.0f - __expf(-sigr * dtq);
        alpha = (T > kTTh) ? alpha : 0.0f;                  // reference gating
        float w = alpha * T;
        T *= (1.0f - alpha);
        wsum += w;
        ar = fmaf(w, rv, ar);
        ag = fmaf(w, gv, ag);
        ab = fmaf(w, bv, ab);

        q0 = m0; q1 = m1; fx = nfx; fy = nfy; fz = nfz;
    }

    pRGBW[j] = make_float4(ar, ag, ab, wsum);
    pT[j] = T;
}

// ---------------- merge ---------------------------------------------------
template <int SPLIT>
__global__ __launch_bounds__(256) void merge_k(
    const float4* __restrict__ pRGBW, const float* __restrict__ pT,
    const int* __restrict__ perm, const float* __restrict__ bg,
    float* __restrict__ out)
{
    int k = blockIdx.x * 256 + threadIdx.x;
    if (k >= kNRays) return;
    float4 a = pRGBW[k];
    float ar = a.x, ag = a.y, ab = a.z, ws = a.w;
    float Tp = pT[k];
    #pragma unroll
    for (int s = 1; s < SPLIT; ++s) {
        float4 b = pRGBW[k + s * kNRays];
        ar = fmaf(Tp, b.x, ar); ag = fmaf(Tp, b.y, ag);
        ab = fmaf(Tp, b.z, ab); ws = fmaf(Tp, b.w, ws);
        Tp *= pT[k + s * kNRays];
    }
    const float inv = 1.0f / 255.0f;
    ar *= inv; ag *= inv; ab *= inv;
    int   ray = perm[k];
    float omw = 1.0f - ws;
    out[3 * ray + 0] = fminf(fmaxf(fmaf(omw, bg[0], ar), 0.0f), 1.0f);
    out[3 * ray + 1] = fminf(fmaxf(fmaf(omw, bg[1], ag), 0.0f), 1.0f);
    out[3 * ray + 2] = fminf(fmaxf(fmaf(omw, bg[2], ab), 0.0f), 1.0f);
}

// ---------------- Tier C: round-2 f16 z-pair path -------------------------
__device__ inline unsigned pack2h(float a, float b) {
    return (unsigned)__half_as_ushort(__float2half_rn(a))
         | ((unsigned)__half_as_ushort(__float2half_rn(b)) << 16);
}
__device__ inline float2 up2h(unsigned u) {
    __half2 h = *reinterpret_cast<const __half2*>(&u);
    return __half22float2(h);
}

__global__ __launch_bounds__(256) void repack_half_k(
    const float* __restrict__ sig, const float* __restrict__ rgb,
    uint2* __restrict__ out)
{
    int i = blockIdx.x * 256 + threadIdx.x;
    if (i >= kG3) return;
    out[i] = make_uint2(pack2h(sig[i], rgb[3 * i + 0]),
                        pack2h(rgb[3 * i + 1], rgb[3 * i + 2]));
}

__global__ __launch_bounds__(256) void render_sorted_k(
    const float* __restrict__ rays_o, const float* __restrict__ rays_d,
    const uint2* __restrict__ grid, const int* __restrict__ perm,
    const float* __restrict__ bg, float* __restrict__ out)
{
    int j = blockIdx.x * 256 + threadIdx.x;
    if (j >= kNRays) return;
    int ray = perm[j];
    float ox = rays_o[3 * ray + 0], oy = rays_o[3 * ray + 1], oz = rays_o[3 * ray + 2];
    float dx = rays_d[3 * ray + 0], dy = rays_d[3 * ray + 1], dz = rays_d[3 * ray + 2];
    float near_, far_;
    slabNearFar(ox, oy, oz, dx, dy, dz, near_, far_);
    float dt = (far_ - near_) * (1.0f / (float)kSteps);
    float T = 1.0f, wsum = 0.0f, accr = 0.0f, accg = 0.0f, accb = 0.0f;
    for (int s = 0; s < kSteps; ++s) {
        int c; float fx, fy, fz;
        stepAddr(near_, dt, ox, oy, oz, dx, dy, dz, s, c, fx, fy, fz);
        uint4 pa = *reinterpret_cast<const uint4*>(grid + c);
        uint4 pb = *reinterpret_cast<const uint4*>(grid + c + kG);
        uint4 pc = *reinterpret_cast<const uint4*>(grid + c + kG * kG);
        uint4 pd = *reinterpret_cast<const uint4*>(grid + c + kG * kG + kG);
        float w0x = 1.0f - fx, w0y = 1.0f - fy, w0z = 1.0f - fz;
        float wa = w0x * w0y * w0z, wb = w0x * w0y * fz;
        float wc = w0x * fy * w0z,  wd = w0x * fy * fz;
        float we = fx * w0y * w0z,  wf = fx * w0y * fz;
        float wg = fx * fy * w0z,   wh = fx * fy * fz;
        float2 srA0 = up2h(pa.x), gbA0 = up2h(pa.y), srA1 = up2h(pa.z), gbA1 = up2h(pa.w);
        float2 srB0 = up2h(pb.x), gbB0 = up2h(pb.y), srB1 = up2h(pb.z), gbB1 = up2h(pb.w);
        float2 srC0 = up2h(pc.x), gbC0 = up2h(pc.y), srC1 = up2h(pc.z), gbC1 = up2h(pc.w);
        float2 srD0 = up2h(pd.x), gbD0 = up2h(pd.y), srD1 = up2h(pd.z), gbD1 = up2h(pd.w);
        float sv = wa*srA0.x + wb*srA1.x + wc*srB0.x + wd*srB1.x
                 + we*srC0.x + wf*srC1.x + wg*srD0.x + wh*srD1.x;
        float rv = wa*srA0.y + wb*srA1.y + wc*srB0.y + wd*srB1.y
                 + we*srC0.y + wf*srC1.y + wg*srD0.y + wh*srD1.y;
        float gv = wa*gbA0.x + wb*gbA1.x + wc*gbB0.x + wd*gbB1.x
                 + we*gbC0.x + wf*gbC1.x + wg*gbD0.x + wh*gbD1.x;
        float bv = wa*gbA0.y + wb*gbA1.y + wc*gbB0.y + wd*gbB1.y
                 + we*gbC0.y + wf*gbC1.y + wg*gbD0.y + wh*gbD1.y;
        float sig = (sv > 0.01f) ? sv : 0.0f;
        float alpha = 1.0f - __expf(-sig * dt);
        float w = alpha * T;
        T *= (1.0f - alpha);
        wsum += w;
        accr = fmaf(w, rv, accr); accg = fmaf(w, gv, accg); accb = fmaf(w, bv, accb);
        if (T <= kTTh) break;
    }
    float omw = 1.0f - wsum;
    out[3 * ray + 0] = fminf(fmaxf(fmaf(omw, bg[0], accr), 0.0f), 1.0f);
    out[3 * ray + 1] = fminf(fmaxf(fmaf(omw, bg[1], accg), 0.0f), 1.0f);
    out[3 * ray + 2] = fminf(fmaxf(fmaf(omw, bg[2], accb), 0.0f), 1.0f);
}

// ---------------- Tier D: plain fallback ----------------------------------
__global__ __launch_bounds__(256) void render_plain_k(
    const float* __restrict__ rays_o, const float* __restrict__ rays_d,
    const float* __restrict__ sgrid, const float* __restrict__ cgrid,
    const float* __restrict__ bg, float* __restrict__ out)
{
    int i = blockIdx.x * 256 + threadIdx.x;
    if (i >= kNRays) return;
    float ox = rays_o[3 * i + 0], oy = rays_o[3 * i + 1], oz = rays_o[3 * i + 2];
    float dx = rays_d[3 * i + 0], dy = rays_d[3 * i + 1], dz = rays_d[3 * i + 2];
    float near_, far_;
    slabNearFar(ox, oy, oz, dx, dy, dz, near_, far_);
    float dt = (far_ - near_) * (1.0f / (float)kSteps);
    float T = 1.0f, wsum = 0.0f, accr = 0.0f, accg = 0.0f, accb = 0.0f;
    for (int s = 0; s < kSteps; ++s) {
        int base; float fx, fy, fz;
        stepAddr(near_, dt, ox, oy, oz, dx, dy, dz, s, base, fx, fy, fz);
        float w0x = 1.0f - fx, w0y = 1.0f - fy, w0z = 1.0f - fz;
        float wa = w0x*w0y*w0z, wb = w0x*w0y*fz, wc = w0x*fy*w0z, wd = w0x*fy*fz;
        float we = fx*w0y*w0z,  wf = fx*w0y*fz,  wg = fx*fy*w0z,  wh = fx*fy*fz;
        int i000 = base, i001 = base + 1, i010 = base + kG, i011 = base + kG + 1;
        int i100 = base + kG*kG, i101 = i100 + 1, i110 = i100 + kG, i111 = i110 + 1;
        float sv = wa*sgrid[i000] + wb*sgrid[i001] + wc*sgrid[i010] + wd*sgrid[i011]
                 + we*sgrid[i100] + wf*sgrid[i101] + wg*sgrid[i110] + wh*sgrid[i111];
        float rv = wa*cgrid[3*i000+0] + wb*cgrid[3*i001+0] + wc*cgrid[3*i010+0] + wd*cgrid[3*i011+0]
                 + we*cgrid[3*i100+0] + wf*cgrid[3*i101+0] + wg*cgrid[3*i110+0] + wh*cgrid[3*i111+0];
        float gv = wa*cgrid[3*i000+1] + wb*cgrid[3*i001+1] + wc*cgrid[3*i010+1] + wd*cgrid[3*i011+1]
                 + we*cgrid[3*i100+1] + wf*cgrid[3*i101+1] + wg*cgrid[3*i110+1] + wh*cgrid[3*i111+1];
        float bv = wa*cgrid[3*i000+2] + wb*cgrid[3*i001+2] + wc*cgrid[3*i010+2] + wd*cgrid[3*i011+2]
                 + we*cgrid[3*i100+2] + wf*cgrid[3*i101+2] + wg*cgrid[3*i110+2] + wh*cgrid[3*i111+2];
        float sig = (sv > 0.01f) ? sv : 0.0f;
        float alpha = 1.0f - __expf(-sig * dt);
        float w = alpha * T;
        T *= (1.0f - alpha);
        wsum += w;
        accr = fmaf(w, rv, accr); accg = fmaf(w, gv, accg); accb = fmaf(w, bv, accb);
        if (T <= kTTh) break;
    }
    float omw = 1.0f - wsum;
    out[3 * i + 0] = fminf(fmaxf(fmaf(omw, bg[0], accr), 0.0f), 1.0f);
    out[3 * i + 1] = fminf(fmaxf(fmaf(omw, bg[1], accg), 0.0f), 1.0f);
    out[3 * i + 2] = fminf(fmaxf(fmaf(omw, bg[2], accb), 0.0f), 1.0f);
}

extern "C" void kernel_launch(void* const* d_in, const int* in_sizes, int n_in,
                              void* d_out, int out_size, void* d_ws, size_t ws_size,
                              hipStream_t stream)
{
    const float* rays_o = (const float*)d_in[0];
    const float* rays_d = (const float*)d_in[1];
    const float* sgrid  = (const float*)d_in[2];
    const float* cgrid  = (const float*)d_in[3];
    const float* bg     = (const float*)d_in[4];
    float* out = (float*)d_out;

    // Tier A (radix path sort + SPLIT=4): ~55 MB
    size_t a_grid  = 0;
    size_t a_hlo   = a_grid + (size_t)kG3 * sizeof(uint4);        // 32 MB
    size_t a_hhi   = a_hlo  + (size_t)kRB * sizeof(int);
    size_t a_blo   = a_hhi  + (size_t)kRB * sizeof(int);
    size_t a_bhi   = a_blo  + (size_t)kRB * sizeof(int);
    size_t a_keys  = a_bhi  + (size_t)kRB * sizeof(int);
    size_t a_perm1 = a_keys + (size_t)kNRays * sizeof(int);
    size_t a_perm  = a_perm1 + (size_t)kNRays * sizeof(int);
    size_t a_rgbw  = a_perm + (size_t)kNRays * sizeof(int);
    size_t a_pt    = a_rgbw + (size_t)(4 * kNRays) * sizeof(float4);  // 16 MB
    size_t needA   = a_pt   + (size_t)(4 * kNRays) * sizeof(float);   //  4 MB

    // Tier B (round-3: dir sort + SPLIT=2): ~43.5 MB
    size_t b_grid = 0;
    size_t b_hist = b_grid + (size_t)kG3 * sizeof(uint4);
    size_t b_base = b_hist + (size_t)kNBuckets * sizeof(int);
    size_t b_keys = b_base + (size_t)kNBuckets * sizeof(int);
    size_t b_perm = b_keys + (size_t)kNRays * sizeof(int);
    size_t b_rgbw = b_perm + (size_t)kNRays * sizeof(int);
    size_t b_pt   = b_rgbw + (size_t)(2 * kNRays) * sizeof(float4);
    size_t needB  = b_pt   + (size_t)(2 * kNRays) * sizeof(float);

    // Tier C (round-2: f16 grid): ~18.3 MB
    size_t c_grid = 0;
    size_t c_hist = c_grid + (size_t)kG3 * sizeof(uint2);
    size_t c_base = c_hist + (size_t)kNBuckets * sizeof(int);
    size_t c_keys = c_base + (size_t)kNBuckets * sizeof(int);
    size_t c_perm = c_keys + (size_t)kNRays * sizeof(int);
    size_t needC  = c_perm + (size_t)kNRays * sizeof(int);

    const int RB_BLK = (kNRays + 255) / 256;

    if (ws_size >= needA) {
        char* ws = (char*)d_ws;
        uint4*  grid  = (uint4*)(ws + a_grid);
        int*    hlo   = (int*)(ws + a_hlo);
        int*    hhi   = (int*)(ws + a_hhi);
        int*    blo   = (int*)(ws + a_blo);
        int*    bhi   = (int*)(ws + a_bhi);
        int*    keys  = (int*)(ws + a_keys);
        int*    perm1 = (int*)(ws + a_perm1);
        int*    perm  = (int*)(ws + a_perm);
        float4* rgbw  = (float4*)(ws + a_rgbw);
        float*  pt    = (float*)(ws + a_pt);

        repack_quad_k<<<(kG3 + 255) / 256, 256, 0, stream>>>(sgrid, cgrid, grid);
        zero4096_k<<<(2 * kRB + 255) / 256, 256, 0, stream>>>(hlo);   // hlo+hhi contiguous
        nfkey_k<<<RB_BLK, 256, 0, stream>>>(rays_o, rays_d, keys, hlo, hhi);
        scanT_k<kRB><<<1, 256, 0, stream>>>(hlo, blo);
        scatter_lo_k<<<RB_BLK, 256, 0, stream>>>(keys, blo, perm1);
        scanT_k<kRB><<<1, 256, 0, stream>>>(hhi, bhi);
        scatter_hi_k<<<RB_BLK, 256, 0, stream>>>(keys, perm1, bhi, perm);
        render_q_k<4><<<(4 * kNRays) / 256, 256, 0, stream>>>(
            rays_o, rays_d, grid, perm, rgbw, pt);
        merge_k<4><<<RB_BLK, 256, 0, stream>>>(rgbw, pt, perm, bg, out);
    } else if (ws_size >= needB) {
        char* ws = (char*)d_ws;
        uint4*  grid  = (uint4*)(ws + b_grid);
        int*    hist  = (int*)(ws + b_hist);
        int*    bbase = (int*)(ws + b_base);
        int*    keys  = (int*)(ws + b_keys);
        int*    perm  = (int*)(ws + b_perm);
        float4* rgbw  = (float4*)(ws + b_rgbw);
        float*  pt    = (float*)(ws + b_pt);

        repack_quad_k<<<(kG3 + 255) / 256, 256, 0, stream>>>(sgrid, cgrid, grid);
        zero_hist_k<<<(kNBuckets + 255) / 256, 256, 0, stream>>>(hist);
        key_hist_k<<<RB_BLK, 256, 0, stream>>>(rays_d, keys, hist);
        scanT_k<kNBuckets><<<1, 256, 0, stream>>>(hist, bbase);
        scatter_k<<<RB_BLK, 256, 0, stream>>>(keys, bbase, perm);
        render_q_k<2><<<(2 * kNRays) / 256, 256, 0, stream>>>(
            rays_o, rays_d, grid, perm, rgbw, pt);
        merge_k<2><<<RB_BLK, 256, 0, stream>>>(rgbw, pt, perm, bg, out);
    } else if (ws_size >= needC) {
        char* ws = (char*)d_ws;
        uint2* grid  = (uint2*)(ws + c_grid);
        int*   hist  = (int*)(ws + c_hist);
        int*   bbase = (int*)(ws + c_base);
        int*   keys  = (int*)(ws + c_keys);
        int*   perm  = (int*)(ws + c_perm);
        repack_half_k<<<(kG3 + 255) / 256, 256, 0, stream>>>(sgrid, cgrid, grid);
        zero_hist_k<<<(kNBuckets + 255) / 256, 256, 0, stream>>>(hist);
        key_hist_k<<<RB_BLK, 256, 0, stream>>>(rays_d, keys, hist);
        scanT_k<kNBuckets><<<1, 256, 0, stream>>>(hist, bbase);
        scatter_k<<<RB_BLK, 256, 0, stream>>>(keys, bbase, perm);
        render_sorted_k<<<RB_BLK, 256, 0, stream>>>(
            rays_o, rays_d, grid, perm, bg, out);
    } else {
        render_plain_k<<<RB_BLK, 256, 0, stream>>>(
            rays_o, rays_d, sgrid, cgrid, bg, out);
    }
}

// Round 5
// 438.822 us; speedup vs baseline: 1.2762x; 1.2762x over previous
//
#include <hip/hip_runtime.h>

// NeRF ray-marching renderer, MI355X — round 5.
//  - ONE-pass counting sort on 18-bit [entry cell 9b][exit cell 9b] key
//    (8x8x8 quantization of AABB hit points) -> path-coherent waves.
//  - Scatter pre-gathers rays into sorted float4 arrays (o,near)/(d,dt):
//    render has no perm gather and no slab math.
//  - LDS-coalesced repack of the u8 quad-cell grid (2 gathers/step render).
//  - XCD chunk swizzle in render (consecutive sorted chunks pinned per XCD).
//  - SPLIT=2 segments, 2-deep software prefetch (4 loads in flight).

constexpr int   kG     = 128;
constexpr int   kG3    = kG * kG * kG;
constexpr int   kSteps = 128;
constexpr int   kNRays = 262144;          // 2^18
constexpr int   kSB    = 1 << 18;         // tier-A sort buckets
constexpr int   kNB    = 128;             // tier-B direction bins
constexpr int   kNBuckets = kNB * kNB;
constexpr float kBminX = -1.0f, kBminY = -0.5f, kBminZ = -1.0f;
constexpr float kBmaxX =  1.0f, kBmaxY =  0.5f, kBmaxZ =  1.0f;
constexpr float kSx = 63.5f, kSy = 127.0f, kSz = 63.5f;   // (G-1)/extent
constexpr float kMinNear = 0.05f;
constexpr float kTTh     = 1e-4f;

// ---------------- shared helpers ------------------------------------------
__device__ __forceinline__ void slabNearFar(
    float ox, float oy, float oz, float dx, float dy, float dz,
    float& near_, float& far_)
{
    float sdx = (fabsf(dx) < 1e-9f) ? 1e-9f : dx;
    float sdy = (fabsf(dy) < 1e-9f) ? 1e-9f : dy;
    float sdz = (fabsf(dz) < 1e-9f) ? 1e-9f : dz;
    float t1x = (kBminX - ox) / sdx, t2x = (kBmaxX - ox) / sdx;
    float t1y = (kBminY - oy) / sdy, t2y = (kBmaxY - oy) / sdy;
    float t1z = (kBminZ - oz) / sdz, t2z = (kBmaxZ - oz) / sdz;
    near_ = fmaxf(fmaxf(fminf(t1x, t2x), fminf(t1y, t2y)), fminf(t1z, t2z));
    far_  = fminf(fminf(fmaxf(t1x, t2x), fmaxf(t1y, t2y)), fmaxf(t1z, t2z));
    near_ = fmaxf(near_, kMinNear);
    far_  = fmaxf(far_, near_ + 1e-6f);
}

__device__ __forceinline__ void stepAddr(
    float near_, float dt, float ox, float oy, float oz,
    float dx, float dy, float dz, int s,
    int& cell, float& fx, float& fy, float& fz)
{
    float t  = fmaf((float)s + 0.5f, dt, near_);
    float px = fmaf(t, dx, ox), py = fmaf(t, dy, oy), pz = fmaf(t, dz, oz);
    float ux = fminf(fmaxf((px - kBminX) * kSx, 0.0f), 127.0f);
    float uy = fminf(fmaxf((py - kBminY) * kSy, 0.0f), 127.0f);
    float uz = fminf(fmaxf((pz - kBminZ) * kSz, 0.0f), 127.0f);
    float u0x = fminf(floorf(ux), 126.0f);
    float u0y = fminf(floorf(uy), 126.0f);
    float u0z = fminf(floorf(uz), 126.0f);
    fx = ux - u0x; fy = uy - u0y; fz = uz - u0z;
    cell = ((int)u0x << 14) + ((int)u0y << 7) + (int)u0z;
}

__device__ __forceinline__ unsigned packvox(
    const float* __restrict__ sig, const float* __restrict__ rgb, int idx)
{
    unsigned s = (unsigned)__float2int_rn(fminf(fmaxf(sig[idx], 0.f), 1.f) * 255.f);
    unsigned r = (unsigned)__float2int_rn(fminf(fmaxf(rgb[3*idx+0], 0.f), 1.f) * 255.f);
    unsigned g = (unsigned)__float2int_rn(fminf(fmaxf(rgb[3*idx+1], 0.f), 1.f) * 255.f);
    unsigned b = (unsigned)__float2int_rn(fminf(fmaxf(rgb[3*idx+2], 0.f), 1.f) * 255.f);
    return s | (r << 8) | (g << 16) | (b << 24);
}

// ---------------- LDS-coalesced quad repack -------------------------------
// Block = (ix, iy0): packs voxel rows (iy0, iy0+1) into LDS, emits 128 cells.
__global__ __launch_bounds__(128) void repack_lds_k(
    const float* __restrict__ sig, const float* __restrict__ rgb,
    uint4* __restrict__ out)
{
    __shared__ unsigned row[2][kG];
    int ix  = blockIdx.x >> 7;
    int iy0 = blockIdx.x & 127;
    int iy1 = min(iy0 + 1, 127);
    int z   = threadIdx.x;
    row[0][z] = packvox(sig, rgb, (ix << 14) + (iy0 << 7) + z);
    row[1][z] = packvox(sig, rgb, (ix << 14) + (iy1 << 7) + z);
    __syncthreads();
    int z1 = min(z + 1, 127);
    out[(ix << 14) + (iy0 << 7) + z] =
        make_uint4(row[0][z], row[0][z1], row[1][z], row[1][z1]);
}

// ---------------- generic zero --------------------------------------------
__global__ __launch_bounds__(256) void zero_k(int* __restrict__ p, int n)
{
    int i = blockIdx.x * 256 + threadIdx.x;
    if (i < n) p[i] = 0;
}

// ---------------- Tier-A: 18-bit entry/exit counting sort -----------------
__device__ __forceinline__ int cell9(float x, float y, float z)
{
    int cx = min(7, max(0, (int)((x - kBminX) * 4.0f)));
    int cy = min(7, max(0, (int)((y - kBminY) * 8.0f)));
    int cz = min(7, max(0, (int)((z - kBminZ) * 4.0f)));
    return (cx << 6) | (cy << 3) | cz;
}

__device__ __forceinline__ int pathKey(
    const float* __restrict__ rays_o, const float* __restrict__ rays_d, int i,
    float& ox, float& oy, float& oz, float& dx, float& dy, float& dz,
    float& near_, float& far_)
{
    ox = rays_o[3 * i + 0]; oy = rays_o[3 * i + 1]; oz = rays_o[3 * i + 2];
    dx = rays_d[3 * i + 0]; dy = rays_d[3 * i + 1]; dz = rays_d[3 * i + 2];
    slabNearFar(ox, oy, oz, dx, dy, dz, near_, far_);
    int ke = cell9(fmaf(near_, dx, ox), fmaf(near_, dy, oy), fmaf(near_, dz, oz));
    int kx = cell9(fmaf(far_,  dx, ox), fmaf(far_,  dy, oy), fmaf(far_,  dz, oz));
    return (ke << 9) | kx;
}

__global__ __launch_bounds__(256) void hist18_k(
    const float* __restrict__ rays_o, const float* __restrict__ rays_d,
    int* __restrict__ hist)
{
    int i = blockIdx.x * 256 + threadIdx.x;
    if (i >= kNRays) return;
    float ox, oy, oz, dx, dy, dz, near_, far_;
    int key = pathKey(rays_o, rays_d, i, ox, oy, oz, dx, dy, dz, near_, far_);
    atomicAdd(&hist[key], 1);
}

// in-place exclusive scan of NB ints, one 256-thread block
template <int NB>
__global__ __launch_bounds__(256) void scan_inplace_k(int* __restrict__ h)
{
    __shared__ int part[256];
    constexpr int PER = NB / 256;
    int t = threadIdx.x;
    int s = 0;
    for (int k = 0; k < PER; ++k) s += h[t * PER + k];
    part[t] = s;
    __syncthreads();
    if (t == 0) {
        int run = 0;
        for (int k = 0; k < 256; ++k) { int v = part[k]; part[k] = run; run += v; }
    }
    __syncthreads();
    int run = part[t];
    for (int k = 0; k < PER; ++k) {
        int idx = t * PER + k;
        int v = h[idx];
        h[idx] = run;
        run += v;
    }
}

__global__ __launch_bounds__(256) void scatter18_k(
    const float* __restrict__ rays_o, const float* __restrict__ rays_d,
    int* __restrict__ base, int* __restrict__ perm,
    float4* __restrict__ so4, float4* __restrict__ sd4)
{
    int i = blockIdx.x * 256 + threadIdx.x;
    if (i >= kNRays) return;
    float ox, oy, oz, dx, dy, dz, near_, far_;
    int key = pathKey(rays_o, rays_d, i, ox, oy, oz, dx, dy, dz, near_, far_);
    float dt = (far_ - near_) * (1.0f / (float)kSteps);
    int pos = atomicAdd(&base[key], 1);
    perm[pos] = i;
    so4[pos] = make_float4(ox, oy, oz, near_);
    sd4[pos] = make_float4(dx, dy, dz, dt);
}

// ---------------- Tier-A render: sorted rays, swizzle, 2-deep PF ----------
#define UB0(u) ((float)((u) & 0xffu))
#define UB1(u) ((float)(((u) >> 8) & 0xffu))
#define UB2(u) ((float)(((u) >> 16) & 0xffu))
#define UB3(u) ((float)((u) >> 24))

__global__ __launch_bounds__(256, 8) void render_s2_k(
    const float4* __restrict__ so4, const float4* __restrict__ sd4,
    const uint4* __restrict__ grid,
    float4* __restrict__ pRGBW, float* __restrict__ pT)
{
    // 2048 blocks; bijective XCD chunk swizzle (2048 % 8 == 0)
    int bid = blockIdx.x;
    int swz = (bid & 7) * (2048 >> 3) + (bid >> 3);
    int j   = swz * 256 + (int)threadIdx.x;     // [0, 2*kNRays)
    int seg = j >> 18;
    int sj  = j & (kNRays - 1);

    float4 o4 = so4[sj], d4 = sd4[sj];
    float ox = o4.x, oy = o4.y, oz = o4.z, near_ = o4.w;
    float dx = d4.x, dy = d4.y, dz = d4.z, dt = d4.w;
    float dtq = dt * (1.0f / 255.0f);

    const int nsteps = kSteps / 2;
    const int s0 = seg * nsteps;

    int c;
    float f0x, f0y, f0z, f1x, f1y, f1z, f2x, f2y, f2z;
    stepAddr(near_, dt, ox, oy, oz, dx, dy, dz, s0, c, f0x, f0y, f0z);
    uint4 q0 = grid[c], q1 = grid[c + (1 << 14)];
    stepAddr(near_, dt, ox, oy, oz, dx, dy, dz, s0 + 1, c, f1x, f1y, f1z);
    uint4 m0 = grid[c], m1 = grid[c + (1 << 14)];

    float T = 1.0f, wsum = 0.0f, ar = 0.0f, ag = 0.0f, ab = 0.0f;

    for (int s = 0; s < nsteps; ++s) {
        int sn = s0 + min(s + 2, nsteps - 1);
        stepAddr(near_, dt, ox, oy, oz, dx, dy, dz, sn, c, f2x, f2y, f2z);
        uint4 n0 = grid[c], n1 = grid[c + (1 << 14)];

        float wz0 = 1.0f - f0z, wy0 = 1.0f - f0y;
        float w00 = wy0 * wz0, w01 = wy0 * f0z, w10 = f0y * wz0, w11 = f0y * f0z;

        float sA = w00 * UB0(q0.x) + w01 * UB0(q0.y) + w10 * UB0(q0.z) + w11 * UB0(q0.w);
        float sB = w00 * UB0(q1.x) + w01 * UB0(q1.y) + w10 * UB0(q1.z) + w11 * UB0(q1.w);
        float rA = w00 * UB1(q0.x) + w01 * UB1(q0.y) + w10 * UB1(q0.z) + w11 * UB1(q0.w);
        float rB = w00 * UB1(q1.x) + w01 * UB1(q1.y) + w10 * UB1(q1.z) + w11 * UB1(q1.w);
        float gA = w00 * UB2(q0.x) + w01 * UB2(q0.y) + w10 * UB2(q0.z) + w11 * UB2(q0.w);
        float gB = w00 * UB2(q1.x) + w01 * UB2(q1.y) + w10 * UB2(q1.z) + w11 * UB2(q1.w);
        float bA = w00 * UB3(q0.x) + w01 * UB3(q0.y) + w10 * UB3(q0.z) + w11 * UB3(q0.w);
        float bB = w00 * UB3(q1.x) + w01 * UB3(q1.y) + w10 * UB3(q1.z) + w11 * UB3(q1.w);

        float sv = fmaf(f0x, sB - sA, sA);      // raw counts in [0,255]
        float rv = fmaf(f0x, rB - rA, rA);
        float gv = fmaf(f0x, gB - gA, gA);
        float bv = fmaf(f0x, bB - bA, bA);

        float sigr  = (sv > 2.55f) ? sv : 0.0f;            // sigma > 0.01
        float alpha = 1.0f - __expf(-sigr * dtq);
        alpha = (T > kTTh) ? alpha : 0.0f;                  // reference gating
        float w = alpha * T;
        T *= (1.0f - alpha);
        wsum += w;
        ar = fmaf(w, rv, ar);
        ag = fmaf(w, gv, ag);
        ab = fmaf(w, bv, ab);

        q0 = m0; q1 = m1; m0 = n0; m1 = n1;
        f0x = f1x; f0y = f1y; f0z = f1z;
        f1x = f2x; f1y = f2y; f1z = f2z;
    }

    pRGBW[j] = make_float4(ar, ag, ab, wsum);
    pT[j] = T;
}

// ---------------- merge (SPLIT=2) -----------------------------------------
__global__ __launch_bounds__(256) void merge2_k(
    const float4* __restrict__ pRGBW, const float* __restrict__ pT,
    const int* __restrict__ perm, const float* __restrict__ bg,
    float* __restrict__ out)
{
    int k = blockIdx.x * 256 + threadIdx.x;
    if (k >= kNRays) return;
    float4 a = pRGBW[k];
    float4 b = pRGBW[k + kNRays];
    float T0 = pT[k];
    float ar = fmaf(T0, b.x, a.x), ag = fmaf(T0, b.y, a.y);
    float ab2 = fmaf(T0, b.z, a.z), ws = fmaf(T0, b.w, a.w);
    const float inv = 1.0f / 255.0f;
    int ray = perm[k];
    float omw = 1.0f - ws;
    out[3 * ray + 0] = fminf(fmaxf(fmaf(omw, bg[0], ar * inv), 0.0f), 1.0f);
    out[3 * ray + 1] = fminf(fmaxf(fmaf(omw, bg[1], ag * inv), 0.0f), 1.0f);
    out[3 * ray + 2] = fminf(fmaxf(fmaf(omw, bg[2], ab2 * inv), 0.0f), 1.0f);
}

// ---------------- Tier-B: round-3 dir sort path ---------------------------
__global__ __launch_bounds__(256) void key_hist_k(
    const float* __restrict__ rays_d, int* __restrict__ keys,
    int* __restrict__ hist)
{
    int i = blockIdx.x * 256 + threadIdx.x;
    if (i >= kNRays) return;
    float dx = rays_d[3 * i + 0], dy = rays_d[3 * i + 1];
    int qx = (int)((dx * 0.625f + 0.5f) * (float)kNB);
    int qy = (int)((dy * 0.625f + 0.5f) * (float)kNB);
    qx = min(kNB - 1, max(0, qx));
    qy = min(kNB - 1, max(0, qy));
    int key = qx * kNB + qy;
    keys[i] = key;
    atomicAdd(&hist[key], 1);
}

__global__ __launch_bounds__(256) void scatter_k(
    const int* __restrict__ keys, int* __restrict__ base,
    int* __restrict__ perm)
{
    int i = blockIdx.x * 256 + threadIdx.x;
    if (i >= kNRays) return;
    int pos = atomicAdd(&base[keys[i]], 1);
    perm[pos] = i;
}

__global__ __launch_bounds__(256, 8) void render_q2_k(
    const float* __restrict__ rays_o, const float* __restrict__ rays_d,
    const uint4* __restrict__ grid, const int* __restrict__ perm,
    float4* __restrict__ pRGBW, float* __restrict__ pT)
{
    int j = blockIdx.x * 256 + threadIdx.x;
    if (j >= kNRays * 2) return;
    int seg = j >> 18;
    int sj  = j & (kNRays - 1);
    int ray = perm[sj];

    float ox = rays_o[3 * ray + 0], oy = rays_o[3 * ray + 1], oz = rays_o[3 * ray + 2];
    float dx = rays_d[3 * ray + 0], dy = rays_d[3 * ray + 1], dz = rays_d[3 * ray + 2];
    float near_, far_;
    slabNearFar(ox, oy, oz, dx, dy, dz, near_, far_);
    float dt  = (far_ - near_) * (1.0f / (float)kSteps);
    float dtq = dt * (1.0f / 255.0f);

    const int nsteps = kSteps / 2;
    const int s0     = seg * nsteps;

    int   c;  float fx, fy, fz;
    stepAddr(near_, dt, ox, oy, oz, dx, dy, dz, s0, c, fx, fy, fz);
    uint4 q0 = grid[c];
    uint4 q1 = grid[c + (1 << 14)];

    float T = 1.0f, wsum = 0.0f, ar = 0.0f, ag = 0.0f, ab = 0.0f;

    for (int s = 0; s < nsteps; ++s) {
        int   cn; float nfx, nfy, nfz;
        int   sn = s0 + min(s + 1, nsteps - 1);
        stepAddr(near_, dt, ox, oy, oz, dx, dy, dz, sn, cn, nfx, nfy, nfz);
        uint4 m0 = grid[cn];
        uint4 m1 = grid[cn + (1 << 14)];

        float wz0 = 1.0f - fz, wy0 = 1.0f - fy;
        float w00 = wy0 * wz0, w01 = wy0 * fz, w10 = fy * wz0, w11 = fy * fz;

        float sA = w00 * UB0(q0.x) + w01 * UB0(q0.y) + w10 * UB0(q0.z) + w11 * UB0(q0.w);
        float sB = w00 * UB0(q1.x) + w01 * UB0(q1.y) + w10 * UB0(q1.z) + w11 * UB0(q1.w);
        float rA = w00 * UB1(q0.x) + w01 * UB1(q0.y) + w10 * UB1(q0.z) + w11 * UB1(q0.w);
        float rB = w00 * UB1(q1.x) + w01 * UB1(q1.y) + w10 * UB1(q1.z) + w11 * UB1(q1.w);
        float gA = w00 * UB2(q0.x) + w01 * UB2(q0.y) + w10 * UB2(q0.z) + w11 * UB2(q0.w);
        float gB = w00 * UB2(q1.x) + w01 * UB2(q1.y) + w10 * UB2(q1.z) + w11 * UB2(q1.w);
        float bA = w00 * UB3(q0.x) + w01 * UB3(q0.y) + w10 * UB3(q0.z) + w11 * UB3(q0.w);
        float bB = w00 * UB3(q1.x) + w01 * UB3(q1.y) + w10 * UB3(q1.z) + w11 * UB3(q1.w);

        float sv = fmaf(fx, sB - sA, sA);
        float rv = fmaf(fx, rB - rA, rA);
        float gv = fmaf(fx, gB - gA, gA);
        float bv = fmaf(fx, bB - bA, bA);

        float sigr  = (sv > 2.55f) ? sv : 0.0f;
        float alpha = 1.0f - __expf(-sigr * dtq);
        alpha = (T > kTTh) ? alpha : 0.0f;
        float w = alpha * T;
        T *= (1.0f - alpha);
        wsum += w;
        ar = fmaf(w, rv, ar);
        ag = fmaf(w, gv, ag);
        ab = fmaf(w, bv, ab);

        q0 = m0; q1 = m1; fx = nfx; fy = nfy; fz = nfz;
    }

    pRGBW[j] = make_float4(ar, ag, ab, wsum);
    pT[j] = T;
}

// ---------------- Tier-D: plain fallback ----------------------------------
__global__ __launch_bounds__(256) void render_plain_k(
    const float* __restrict__ rays_o, const float* __restrict__ rays_d,
    const float* __restrict__ sgrid, const float* __restrict__ cgrid,
    const float* __restrict__ bg, float* __restrict__ out)
{
    int i = blockIdx.x * 256 + threadIdx.x;
    if (i >= kNRays) return;
    float ox = rays_o[3 * i + 0], oy = rays_o[3 * i + 1], oz = rays_o[3 * i + 2];
    float dx = rays_d[3 * i + 0], dy = rays_d[3 * i + 1], dz = rays_d[3 * i + 2];
    float near_, far_;
    slabNearFar(ox, oy, oz, dx, dy, dz, near_, far_);
    float dt = (far_ - near_) * (1.0f / (float)kSteps);
    float T = 1.0f, wsum = 0.0f, accr = 0.0f, accg = 0.0f, accb = 0.0f;
    for (int s = 0; s < kSteps; ++s) {
        int base; float fx, fy, fz;
        stepAddr(near_, dt, ox, oy, oz, dx, dy, dz, s, base, fx, fy, fz);
        float w0x = 1.0f - fx, w0y = 1.0f - fy, w0z = 1.0f - fz;
        float wa = w0x*w0y*w0z, wb = w0x*w0y*fz, wc = w0x*fy*w0z, wd = w0x*fy*fz;
        float we = fx*w0y*w0z,  wf = fx*w0y*fz,  wg = fx*fy*w0z,  wh = fx*fy*fz;
        int i000 = base, i001 = base + 1, i010 = base + kG, i011 = base + kG + 1;
        int i100 = base + kG*kG, i101 = i100 + 1, i110 = i100 + kG, i111 = i110 + 1;
        float sv = wa*sgrid[i000] + wb*sgrid[i001] + wc*sgrid[i010] + wd*sgrid[i011]
                 + we*sgrid[i100] + wf*sgrid[i101] + wg*sgrid[i110] + wh*sgrid[i111];
        float rv = wa*cgrid[3*i000+0] + wb*cgrid[3*i001+0] + wc*cgrid[3*i010+0] + wd*cgrid[3*i011+0]
                 + we*cgrid[3*i100+0] + wf*cgrid[3*i101+0] + wg*cgrid[3*i110+0] + wh*cgrid[3*i111+0];
        float gv = wa*cgrid[3*i000+1] + wb*cgrid[3*i001+1] + wc*cgrid[3*i010+1] + wd*cgrid[3*i011+1]
                 + we*cgrid[3*i100+1] + wf*cgrid[3*i101+1] + wg*cgrid[3*i110+1] + wh*cgrid[3*i111+1];
        float bv = wa*cgrid[3*i000+2] + wb*cgrid[3*i001+2] + wc*cgrid[3*i010+2] + wd*cgrid[3*i011+2]
                 + we*cgrid[3*i100+2] + wf*cgrid[3*i101+2] + wg*cgrid[3*i110+2] + wh*cgrid[3*i111+2];
        float sig = (sv > 0.01f) ? sv : 0.0f;
        float alpha = 1.0f - __expf(-sig * dt);
        float w = alpha * T;
        T *= (1.0f - alpha);
        wsum += w;
        accr = fmaf(w, rv, accr); accg = fmaf(w, gv, accg); accb = fmaf(w, bv, accb);
        if (T <= kTTh) break;
    }
    float omw = 1.0f - wsum;
    out[3 * i + 0] = fminf(fmaxf(fmaf(omw, bg[0], accr), 0.0f), 1.0f);
    out[3 * i + 1] = fminf(fmaxf(fmaf(omw, bg[1], accg), 0.0f), 1.0f);
    out[3 * i + 2] = fminf(fmaxf(fmaf(omw, bg[2], accb), 0.0f), 1.0f);
}

extern "C" void kernel_launch(void* const* d_in, const int* in_sizes, int n_in,
                              void* d_out, int out_size, void* d_ws, size_t ws_size,
                              hipStream_t stream)
{
    const float* rays_o = (const float*)d_in[0];
    const float* rays_d = (const float*)d_in[1];
    const float* sgrid  = (const float*)d_in[2];
    const float* cgrid  = (const float*)d_in[3];
    const float* bg     = (const float*)d_in[4];
    float* out = (float*)d_out;

    const int RB_BLK = kNRays / 256;   // 1024

    // Tier A: grid | hist | perm | so4 | sd4 | rgbw | pT  = 52.0 MiB
    size_t a_grid = 0;
    size_t a_hist = a_grid + (size_t)kG3 * sizeof(uint4);            // 32 MiB
    size_t a_perm = a_hist + (size_t)kSB * sizeof(int);              // +1 MiB
    size_t a_so4  = a_perm + (size_t)kNRays * sizeof(int);           // +1 MiB
    size_t a_sd4  = a_so4  + (size_t)kNRays * sizeof(float4);        // +4 MiB
    size_t a_rgbw = a_sd4  + (size_t)kNRays * sizeof(float4);        // +4 MiB
    size_t a_pt   = a_rgbw + (size_t)(2 * kNRays) * sizeof(float4);  // +8 MiB
    size_t needA  = a_pt   + (size_t)(2 * kNRays) * sizeof(float);   // +2 MiB

    // Tier B: grid | hist | keys | perm | rgbw | pT  = 44.1 MiB
    size_t b_grid = 0;
    size_t b_hist = b_grid + (size_t)kG3 * sizeof(uint4);
    size_t b_keys = b_hist + (size_t)kNBuckets * sizeof(int);
    size_t b_perm = b_keys + (size_t)kNRays * sizeof(int);
    size_t b_rgbw = b_perm + (size_t)kNRays * sizeof(int);
    size_t b_pt   = b_rgbw + (size_t)(2 * kNRays) * sizeof(float4);
    size_t needB  = b_pt   + (size_t)(2 * kNRays) * sizeof(float);

    if (ws_size >= needA) {
        char* ws = (char*)d_ws;
        uint4*  grid = (uint4*)(ws + a_grid);
        int*    hist = (int*)(ws + a_hist);
        int*    perm = (int*)(ws + a_perm);
        float4* so4  = (float4*)(ws + a_so4);
        float4* sd4  = (float4*)(ws + a_sd4);
        float4* rgbw = (float4*)(ws + a_rgbw);
        float*  pt   = (float*)(ws + a_pt);

        repack_lds_k<<<kG * kG, 128, 0, stream>>>(sgrid, cgrid, grid);
        zero_k<<<kSB / 256, 256, 0, stream>>>(hist, kSB);
        hist18_k<<<RB_BLK, 256, 0, stream>>>(rays_o, rays_d, hist);
        scan_inplace_k<kSB><<<1, 256, 0, stream>>>(hist);
        scatter18_k<<<RB_BLK, 256, 0, stream>>>(rays_o, rays_d, hist, perm, so4, sd4);
        render_s2_k<<<2 * kNRays / 256, 256, 0, stream>>>(so4, sd4, grid, rgbw, pt);
        merge2_k<<<RB_BLK, 256, 0, stream>>>(rgbw, pt, perm, bg, out);
    } else if (ws_size >= needB) {
        char* ws = (char*)d_ws;
        uint4*  grid = (uint4*)(ws + b_grid);
        int*    hist = (int*)(ws + b_hist);
        int*    keys = (int*)(ws + b_keys);
        int*    perm = (int*)(ws + b_perm);
        float4* rgbw = (float4*)(ws + b_rgbw);
        float*  pt   = (float*)(ws + b_pt);

        repack_lds_k<<<kG * kG, 128, 0, stream>>>(sgrid, cgrid, grid);
        zero_k<<<kNBuckets / 256, 256, 0, stream>>>(hist, kNBuckets);
        key_hist_k<<<RB_BLK, 256, 0, stream>>>(rays_d, keys, hist);
        scan_inplace_k<kNBuckets><<<1, 256, 0, stream>>>(hist);
        scatter_k<<<RB_BLK, 256, 0, stream>>>(keys, hist, perm);
        render_q2_k<<<2 * kNRays / 256, 256, 0, stream>>>(
            rays_o, rays_d, grid, perm, rgbw, pt);
        merge2_k<<<RB_BLK, 256, 0, stream>>>(rgbw, pt, perm, bg, out);
    } else {
        render_plain_k<<<RB_BLK, 256, 0, stream>>>(
            rays_o, rays_d, sgrid, cgrid, bg, out);
    }
}